// Round 1
// 1737.000 us; speedup vs baseline: 1.0135x; 1.0135x over previous
//
#include <hip/hip_runtime.h>

#define N 10000
#define P 2000
#define CT 10
#define E_EDGES 320000
#define DAE0 100
#define DAE1 20
#define GAE0 32
#define GAE1 20
#define FCAT 40
#define FEAT 64
#define PCT 20000  // P*CT

__device__ __forceinline__ float celu1(float v) {
  return v > 0.0f ? v : (expf(v) - 1.0f);
}

// ---------------- prep: deg init + loss accum zero ----------------
__global__ void k_prep(float* deg, float* loss) {
  int i = blockIdx.x * 256 + threadIdx.x;
  if (i < N) deg[i] = 1.0f;
  if (i < 4) loss[i] = 0.0f;
}

__global__ void k_degscat(const int* ei, const float* w, float* deg) {
  int e = blockIdx.x * 256 + threadIdx.x;  // E exact multiple of 256
  atomicAdd(&deg[ei[E_EDGES + e]], w[e]);
}

__global__ void k_dinv(const float* deg, float* dinv) {
  int i = blockIdx.x * 256 + threadIdx.x;
  if (i < N) dinv[i] = rsqrtf(deg[i]);
}

// ---------------- K1: h1 = celu(x @ W1 + b1), split-K x5 ----------------
// tile 80 rows x 100 cols, BK=40, 320 threads, thread = 5x5 outputs
__global__ __launch_bounds__(320) void k1_main(const float* __restrict__ x,
                                               const float* __restrict__ W1,
                                               float* __restrict__ h1p) {
  __shared__ float xs[80][40];
  __shared__ float wsh[40][100];
  int tid = threadIdx.x;
  int rowb = blockIdx.x * 80;
  int kbase = blockIdx.y * 400;  // 5 splits x 400
  int ty = tid / 20, tx = tid % 20;
  float acc[5][5];
#pragma unroll
  for (int i = 0; i < 5; i++)
#pragma unroll
    for (int j = 0; j < 5; j++) acc[i][j] = 0.0f;

  for (int kt = 0; kt < 10; ++kt) {
    int k0 = kbase + kt * 40;
#pragma unroll
    for (int t = 0; t < 3; ++t) {
      int idx = tid + t * 320;
      if (idx < 800) {
        int row = idx / 10, kq = idx % 10;
        float4 v = *(const float4*)&x[(size_t)(rowb + row) * P + k0 + kq * 4];
        *(float4*)&xs[row][kq * 4] = v;
      }
    }
#pragma unroll
    for (int t = 0; t < 4; ++t) {
      int idx = tid + t * 320;
      if (idx < 1000) {
        int k = idx / 25, cq = idx % 25;
        float4 v = *(const float4*)&W1[(size_t)(k0 + k) * DAE0 + cq * 4];
        *(float4*)&wsh[k][cq * 4] = v;
      }
    }
    __syncthreads();
    for (int kk = 0; kk < 40; ++kk) {
      float xa[5], wb[5];
#pragma unroll
      for (int i = 0; i < 5; i++) xa[i] = xs[ty * 5 + i][kk];
#pragma unroll
      for (int j = 0; j < 5; j++) wb[j] = wsh[kk][tx * 5 + j];
#pragma unroll
      for (int i = 0; i < 5; i++)
#pragma unroll
        for (int j = 0; j < 5; j++) acc[i][j] += xa[i] * wb[j];
    }
    __syncthreads();
  }
  float* outp = h1p + (size_t)blockIdx.y * (N * DAE0);
#pragma unroll
  for (int i = 0; i < 5; i++) {
    int row = rowb + ty * 5 + i;
#pragma unroll
    for (int j = 0; j < 5; j++) outp[(size_t)row * DAE0 + tx * 5 + j] = acc[i][j];
  }
}

__global__ void k1_fin(const float* __restrict__ h1p, const float* __restrict__ b1,
                       float* __restrict__ h1) {
  int i = blockIdx.x * 256 + threadIdx.x;
  if (i < N * DAE0) {
    float v = h1p[i] + h1p[N * DAE0 + i] + h1p[2 * N * DAE0 + i] +
              h1p[3 * N * DAE0 + i] + h1p[4 * N * DAE0 + i] + b1[i % DAE0];
    h1[i] = celu1(v);
  }
}

// ---------------- K2: feat_x = celu(h1 @ W2 + b2) ----------------
__global__ void k2(const float* __restrict__ h1, const float* __restrict__ W2,
                   const float* __restrict__ b2, float* __restrict__ fx) {
  int i = blockIdx.x * 256 + threadIdx.x;
  if (i >= N * DAE1) return;
  int row = i / DAE1, c = i % DAE1;
  float acc = b2[c];
  const float* hr = h1 + (size_t)row * DAE0;
#pragma unroll 4
  for (int k = 0; k < DAE0; ++k) acc += hr[k] * W2[k * DAE1 + c];
  fx[i] = celu1(acc);
}

// ---------------- scatter: out = Ŝ xin (self-loop init + edge atomics) ----------------
template <int C>
__global__ void k_self(const float* __restrict__ xin, const float* __restrict__ dinv,
                       float* __restrict__ outp) {
  int i = blockIdx.x * 256 + threadIdx.x;
  if (i >= N * C) return;
  int row = i / C;
  float d = dinv[row];
  outp[i] = d * d * xin[i];
}

template <int C>
__global__ void k_scat(const float* __restrict__ xin, const float* __restrict__ dinv,
                       const int* __restrict__ ei, const float* __restrict__ w,
                       float* __restrict__ outp) {
  int i = blockIdx.x * 256 + threadIdx.x;  // E*C exact multiple of 256
  int e = i / C, c = i % C;
  int src = ei[e], dst = ei[E_EDGES + e];
  float nrm = dinv[src] * dinv[dst] * w[e];
  atomicAdd(&outp[dst * C + c], nrm * xin[src * C + c]);
}

// ---------------- K4: h = relu(sx @ Wf + bf) ----------------
__global__ void k4(const float* __restrict__ sx, const float* __restrict__ Wf,
                   const float* __restrict__ bf, float* __restrict__ h) {
  int i = blockIdx.x * 256 + threadIdx.x;  // N*32 exact
  int row = i / GAE0, c = i % GAE0;
  float acc = bf[c];
  const float* xr = sx + (size_t)row * DAE1;
#pragma unroll
  for (int k = 0; k < DAE1; ++k) acc += xr[k] * Wf[k * GAE0 + c];
  h[i] = fmaxf(acc, 0.0f);
}

// ---------------- K6: mu/logstd/z, feat concat, KL partial ----------------
__global__ void k6(const float* __restrict__ sh, const float* __restrict__ Wm,
                   const float* __restrict__ bm, const float* __restrict__ Wsl,
                   const float* __restrict__ bsl, const float* __restrict__ eps,
                   const float* __restrict__ fx, float* __restrict__ feat,
                   float* __restrict__ loss) {
  __shared__ float red[256];
  int i = blockIdx.x * 256 + threadIdx.x;
  float kle = 0.0f;
  if (i < N * GAE1) {
    int row = i / GAE1, c = i % GAE1;
    float mu = bm[c], ls = bsl[c];
    const float* hr = sh + (size_t)row * GAE0;
#pragma unroll
    for (int k = 0; k < GAE0; ++k) {
      float hv = hr[k];
      mu += hv * Wm[k * GAE1 + c];
      ls += hv * Wsl[k * GAE1 + c];
    }
    ls = fminf(ls, 10.0f);
    float ex = expf(ls);
    float z = mu + eps[i] * ex;
    feat[(size_t)row * FCAT + DAE1 + c] = z;
    feat[(size_t)row * FCAT + c] = fx[i];
    kle = 1.0f + 2.0f * ls - mu * mu - ex * ex;  // exp(2ls) = ex^2
  }
  int t = threadIdx.x;
  red[t] = kle;
  __syncthreads();
  for (int s = 128; s > 0; s >>= 1) {
    if (t < s) red[t] += red[t + s];
    __syncthreads();
  }
  if (t == 0) atomicAdd(&loss[2], red[0]);
}

// ---------------- K7: ct head ----------------
__global__ void k7(const float* __restrict__ feat, const float* __restrict__ Wc,
                   const float* __restrict__ bc, float* __restrict__ out_ct) {
  int row = blockIdx.x * 256 + threadIdx.x;
  if (row >= N) return;
  float acc[CT];
#pragma unroll
  for (int c = 0; c < CT; ++c) acc[c] = bc[c];
  const float* fr = feat + (size_t)row * FCAT;
#pragma unroll
  for (int k = 0; k < FCAT; ++k) {
    float f = fr[k];
#pragma unroll
    for (int c = 0; c < CT; ++c) acc[c] += f * Wc[k * CT + c];
  }
  float s = 0.0f;
#pragma unroll
  for (int c = 0; c < CT; ++c) {
    acc[c] = fmaxf(acc[c], 0.0f);
    s += acc[c];
  }
  float inv = 1.0f / (s + 1e-6f);
#pragma unroll
  for (int c = 0; c < CT; ++c) out_ct[(size_t)row * CT + c] = acc[c] * inv;
}

// ---------------- zg = relu(feat @ Wg + bg) ----------------
__global__ void k_zg(const float* __restrict__ feat, const float* __restrict__ Wg,
                     const float* __restrict__ bg, float* __restrict__ zg) {
  int i = blockIdx.x * 256 + threadIdx.x;  // N*64 exact
  int row = i / FEAT, c = i % FEAT;
  float acc = bg[c];
  const float* fr = feat + (size_t)row * FCAT;
#pragma unroll
  for (int k = 0; k < FCAT; ++k) acc += fr[k] * Wg[k * FEAT + c];
  zg[i] = fmaxf(acc, 0.0f);
}

// ---------------- edge losses ----------------
__global__ void k_edge(const float* __restrict__ zg, const int* __restrict__ ei,
                       const int* __restrict__ nei, const float* __restrict__ w,
                       float* __restrict__ loss) {
  __shared__ float red[256];
  int i = blockIdx.x * 256 + threadIdx.x;  // 2E exact
  bool isPos = i < E_EDGES;
  int e = isPos ? i : i - E_EDGES;
  const int* eidx = isPos ? ei : nei;
  int a = eidx[e], b = eidx[E_EDGES + e];
  const float4* za = (const float4*)(zg + (size_t)a * FEAT);
  const float4* zb = (const float4*)(zg + (size_t)b * FEAT);
  float d = 0.0f;
#pragma unroll
  for (int q = 0; q < FEAT / 4; ++q) {
    float4 xa = za[q], yb = zb[q];
    d += xa.x * yb.x + xa.y * yb.y + xa.z * yb.z + xa.w * yb.w;
  }
  float sig = 1.0f / (1.0f + expf(-d));
  float lpos = 0.0f, lneg = 0.0f;
  if (isPos) {
    float df = sig - w[e];
    lpos = df * df;
  } else {
    lneg = sig * sig;
  }
  int t = threadIdx.x;
  red[t] = lpos;
  __syncthreads();
  for (int s = 128; s > 0; s >>= 1) {
    if (t < s) red[t] += red[t + s];
    __syncthreads();
  }
  if (t == 0) atomicAdd(&loss[0], red[0]);
  __syncthreads();
  red[t] = lneg;
  __syncthreads();
  for (int s = 128; s > 0; s >>= 1) {
    if (t < s) red[t] += red[t + s];
    __syncthreads();
  }
  if (t == 0) atomicAdd(&loss[1], red[0]);
}

__global__ void k_fin(const float* __restrict__ loss, float* __restrict__ out_loss) {
  if (threadIdx.x == 0 && blockIdx.x == 0) {
    float pos = loss[0] / (float)E_EDGES;
    float neg = loss[1] / (float)E_EDGES;
    float kl = -0.5f * loss[2] / (float)N;
    out_loss[0] = pos + neg + kl / (float)N;
  }
}

// ---------------- x_dec = feat @ Wdec + bdec ----------------
// block: 32 col-threads x 20 cols = 640 cols, 8 row-threads x 4 rows = 32 rows
__global__ __launch_bounds__(256) void k_xdec(const float* __restrict__ feat,
                                              const float* __restrict__ Wd,
                                              const float* __restrict__ bd,
                                              float* __restrict__ out_xd) {
  __shared__ float fs[32][40];
  int tid = threadIdx.x;
  int u = tid & 31, r = tid >> 5;
  int rowb = blockIdx.y * 32;
#pragma unroll
  for (int t = 0; t < 5; ++t) {
    int idx = tid + t * 256;  // 1280 exact
    int rr = idx / 40, k = idx - rr * 40;
    int row = rowb + rr;
    fs[rr][k] = (row < N) ? feat[(size_t)row * FCAT + k] : 0.0f;
  }
  __syncthreads();
  int col0 = blockIdx.x * 640 + u * 20;
  if (col0 >= P) return;
  float acc[4][20];
#pragma unroll
  for (int i = 0; i < 4; i++)
#pragma unroll
    for (int j = 0; j < 20; j++) acc[i][j] = 0.0f;
  for (int k = 0; k < FCAT; ++k) {
    const float* wr = Wd + (size_t)k * P + col0;
    float4 w0 = *(const float4*)(wr);
    float4 w1 = *(const float4*)(wr + 4);
    float4 w2 = *(const float4*)(wr + 8);
    float4 w3 = *(const float4*)(wr + 12);
    float4 w4 = *(const float4*)(wr + 16);
    float wv[20] = {w0.x, w0.y, w0.z, w0.w, w1.x, w1.y, w1.z, w1.w,
                    w2.x, w2.y, w2.z, w2.w, w3.x, w3.y, w3.z, w3.w,
                    w4.x, w4.y, w4.z, w4.w};
#pragma unroll
    for (int i = 0; i < 4; i++) {
      float f = fs[r * 4 + i][k];
#pragma unroll
      for (int j = 0; j < 20; j++) acc[i][j] += f * wv[j];
    }
  }
  float bvv[20];
#pragma unroll
  for (int j = 0; j < 20; j++) bvv[j] = bd[col0 + j];
#pragma unroll
  for (int i = 0; i < 4; i++) {
    int row = rowb + r * 4 + i;
    if (row < N) {
#pragma unroll
      for (int q = 0; q < 5; q++) {
        float4 o;
        o.x = acc[i][q * 4 + 0] + bvv[q * 4 + 0];
        o.y = acc[i][q * 4 + 1] + bvv[q * 4 + 1];
        o.z = acc[i][q * 4 + 2] + bvv[q * 4 + 2];
        o.w = acc[i][q * 4 + 3] + bvv[q * 4 + 3];
        *(float4*)&out_xd[(size_t)row * P + col0 + q * 4] = o;
      }
    }
  }
}

// ---------------- pw = group-normalized relu(feat @ Wv + bv) ----------------
// Stores are LDS-staged and flushed lane-contiguous: the old direct path wrote
// 200M scalar f32 at 80B lane stride -> one 64B L2 sector request per 4B store
// (16x write-request amplification). Staged flush: lane u writes col u+q*32 ->
// 4 line requests per wave-instr (optimal). st stride 642 keeps the two
// half-wave rows on disjoint LDS bank sets (4-way aliasing only, benign).
__global__ __launch_bounds__(256) void k_pw(const float* __restrict__ feat,
                                            const float* __restrict__ Wv,
                                            const float* __restrict__ bv,
                                            float* __restrict__ out_pw) {
  __shared__ float fs[32][40];
  __shared__ float st[8][642];
  int tid = threadIdx.x;
  int u = tid & 31, r = tid >> 5;
  int rowb = blockIdx.y * 32;
#pragma unroll
  for (int t = 0; t < 5; ++t) {
    int idx = tid + t * 256;
    int rr = idx / 40, k = idx - rr * 40;
    int row = rowb + rr;
    fs[rr][k] = (row < N) ? feat[(size_t)row * FCAT + k] : 0.0f;
  }
  __syncthreads();
  int cbase = blockIdx.x * 640;
  int col0 = cbase + u * 20;
  // clamp (last partial x-block only): avoids OOB Wv/bv reads; clamped threads'
  // staged values land at st positions >= nvalid and are never flushed.
  if (col0 > PCT - 20) col0 = PCT - 20;
  int nvalid = PCT - cbase;
  if (nvalid > 640) nvalid = 640;
  float acc[4][20];
#pragma unroll
  for (int i = 0; i < 4; i++)
#pragma unroll
    for (int j = 0; j < 20; j++) acc[i][j] = 0.0f;
  for (int k = 0; k < FCAT; ++k) {
    const float* wr = Wv + (size_t)k * PCT + col0;
    float4 w0 = *(const float4*)(wr);
    float4 w1 = *(const float4*)(wr + 4);
    float4 w2 = *(const float4*)(wr + 8);
    float4 w3 = *(const float4*)(wr + 12);
    float4 w4 = *(const float4*)(wr + 16);
    float wv[20] = {w0.x, w0.y, w0.z, w0.w, w1.x, w1.y, w1.z, w1.w,
                    w2.x, w2.y, w2.z, w2.w, w3.x, w3.y, w3.z, w3.w,
                    w4.x, w4.y, w4.z, w4.w};
#pragma unroll
    for (int i = 0; i < 4; i++) {
      float f = fs[r * 4 + i][k];
#pragma unroll
      for (int j = 0; j < 20; j++) acc[i][j] += f * wv[j];
    }
  }
  float bvv[20];
#pragma unroll
  for (int j = 0; j < 20; j++) bvv[j] = bv[col0 + j];
#pragma unroll
  for (int i = 0; i < 4; i++) {
    // normalize (identical FP order to previous version) and stage into LDS
#pragma unroll
    for (int g = 0; g < 2; g++) {
      float v[10];
      float s = 0.0f;
#pragma unroll
      for (int j = 0; j < 10; j++) {
        v[j] = fmaxf(acc[i][g * 10 + j] + bvv[g * 10 + j], 0.0f);
        s += v[j];
      }
      float inv = 1.0f / (s + 1e-6f);
#pragma unroll
      for (int j = 0; j < 10; j++) st[r][u * 20 + g * 10 + j] = v[j] * inv;
    }
    __syncthreads();
    // flush 8 rows (row-local r*4+i) x 640 cols, lane-contiguous
    int row = rowb + r * 4 + i;
    if (row < N) {
      size_t base = (size_t)row * PCT + cbase;
#pragma unroll
      for (int q = 0; q < 20; ++q) {
        int c = u + q * 32;
        if (c < nvalid) out_pw[base + c] = st[r][c];
      }
    }
    __syncthreads();
  }
}

extern "C" void kernel_launch(void* const* d_in, const int* in_sizes, int n_in,
                              void* d_out, int out_size, void* d_ws, size_t ws_size,
                              hipStream_t stream) {
  const float* x    = (const float*)d_in[0];
  const float* ew   = (const float*)d_in[1];
  const float* eps  = (const float*)d_in[2];
  const float* W1   = (const float*)d_in[3];
  const float* b1   = (const float*)d_in[4];
  const float* W2   = (const float*)d_in[5];
  const float* b2   = (const float*)d_in[6];
  const float* Wf   = (const float*)d_in[7];
  const float* bf   = (const float*)d_in[8];
  const float* Wm   = (const float*)d_in[9];
  const float* bm   = (const float*)d_in[10];
  const float* Wsl  = (const float*)d_in[11];
  const float* bsl  = (const float*)d_in[12];
  const float* Wdec = (const float*)d_in[13];
  const float* bdec = (const float*)d_in[14];
  const float* Wg   = (const float*)d_in[15];
  const float* bg   = (const float*)d_in[16];
  const float* Wc   = (const float*)d_in[17];
  const float* bc   = (const float*)d_in[18];
  const float* Wv   = (const float*)d_in[19];
  const float* bv   = (const float*)d_in[20];
  const int* ei     = (const int*)d_in[21];
  const int* nei    = (const int*)d_in[22];

  float* out      = (float*)d_out;
  float* out_ct   = out;
  float* out_xd   = out + (size_t)N * CT;
  float* out_loss = out + (size_t)N * CT + (size_t)N * P;
  float* out_pw   = out_loss + 1;

  float* wsp  = (float*)d_ws;
  float* deg  = wsp; wsp += N;
  float* dinv = wsp; wsp += N;
  float* h1   = wsp; wsp += (size_t)N * DAE0;
  float* h1p  = wsp; wsp += (size_t)5 * N * DAE0;
  float* fx   = wsp; wsp += (size_t)N * DAE1;
  float* sx   = wsp; wsp += (size_t)N * DAE1;
  float* h    = wsp; wsp += (size_t)N * GAE0;
  float* shb  = wsp; wsp += (size_t)N * GAE0;
  float* feat = wsp; wsp += (size_t)N * FCAT;
  float* zg   = wsp; wsp += (size_t)N * FEAT;
  float* loss = wsp; wsp += 4;

  k_prep<<<40, 256, 0, stream>>>(deg, loss);
  k_degscat<<<E_EDGES / 256, 256, 0, stream>>>(ei, ew, deg);
  k_dinv<<<40, 256, 0, stream>>>(deg, dinv);

  k1_main<<<dim3(125, 5), 320, 0, stream>>>(x, W1, h1p);
  k1_fin<<<(N * DAE0 + 255) / 256, 256, 0, stream>>>(h1p, b1, h1);
  k2<<<(N * DAE1 + 255) / 256, 256, 0, stream>>>(h1, W2, b2, fx);

  k_self<DAE1><<<(N * DAE1 + 255) / 256, 256, 0, stream>>>(fx, dinv, sx);
  k_scat<DAE1><<<E_EDGES * DAE1 / 256, 256, 0, stream>>>(fx, dinv, ei, ew, sx);
  k4<<<N * GAE0 / 256, 256, 0, stream>>>(sx, Wf, bf, h);

  k_self<GAE0><<<(N * GAE0 + 255) / 256, 256, 0, stream>>>(h, dinv, shb);
  k_scat<GAE0><<<E_EDGES * GAE0 / 256, 256, 0, stream>>>(h, dinv, ei, ew, shb);

  k6<<<(N * GAE1 + 255) / 256, 256, 0, stream>>>(shb, Wm, bm, Wsl, bsl, eps, fx, feat, loss);
  k7<<<(N + 255) / 256, 256, 0, stream>>>(feat, Wc, bc, out_ct);
  k_zg<<<N * FEAT / 256, 256, 0, stream>>>(feat, Wg, bg, zg);
  k_edge<<<2 * E_EDGES / 256, 256, 0, stream>>>(zg, ei, nei, ew, loss);
  k_fin<<<1, 64, 0, stream>>>(loss, out_loss);

  k_xdec<<<dim3(4, 313), 256, 0, stream>>>(feat, Wdec, bdec, out_xd);
  k_pw<<<dim3(32, 313), 256, 0, stream>>>(feat, Wv, bv, out_pw);
}